// Round 4
// baseline (449.619 us; speedup 1.0000x reference)
//
#include <hip/hip_runtime.h>
#include <hip/hip_bf16.h>
#include <math.h>

#define B_  8
#define D_  256
#define N_  2048
#define M_  2048
#define H_  4

typedef __attribute__((ext_vector_type(8))) short bf16x8;
typedef __attribute__((ext_vector_type(4))) float f32x4;

static __device__ __forceinline__ unsigned short f2bf(float f) {
    __hip_bfloat16 h = __float2bfloat16(f);
    return *reinterpret_cast<unsigned short*>(&h);
}
static __device__ __forceinline__ float bf2f_lo(unsigned int u) {
    return __uint_as_float((u & 0xffffu) << 16);
}
static __device__ __forceinline__ float bf2f_hi(unsigned int u) {
    return __uint_as_float(u & 0xffff0000u);
}

#define GLOAD16(gsrc, ldsbase)                                                     \
    __builtin_amdgcn_global_load_lds(                                              \
        (const __attribute__((address_space(1))) unsigned int*)(gsrc),             \
        (__attribute__((address_space(3))) unsigned int*)(ldsbase), 16, 0, 0)

// ---------------------------------------------------------------------------
// Weight cast/permute + folded-bias kernel.
//  wqp/wkp: rows permuted o' = h*64+dh  (bf16)
//  wv:      natural bf16
//  wcat[:, 0:256] = bf16(W1 left half); right half filled by fold_w
//  w2b:     natural bf16
//  bqp/bkp: permuted fp32 biases
//  bfold[o] = b1[o] + sum_j W1[o][256+j]*bm[j]
// ---------------------------------------------------------------------------
__global__ __launch_bounds__(256) void cvt_w(
    const float* __restrict__ Wq, const float* __restrict__ Wk,
    const float* __restrict__ Wv, const float* __restrict__ W1,
    const float* __restrict__ W2, const float* __restrict__ bq,
    const float* __restrict__ bk, const float* __restrict__ b1,
    const float* __restrict__ bm,
    unsigned short* __restrict__ wqp, unsigned short* __restrict__ wkp,
    unsigned short* __restrict__ wv,  unsigned short* __restrict__ wcat,
    unsigned short* __restrict__ w2b,
    float* __restrict__ bqp, float* __restrict__ bkp, float* __restrict__ bfold)
{
    const int idx = blockIdx.x * 256 + threadIdx.x;
    if (idx < 65536) {
        const int op = idx >> 8, k = idx & 255;
        const int h = op >> 6, dh = op & 63;
        wqp[idx] = f2bf(Wq[(dh*4 + h)*256 + k]);
    } else if (idx < 131072) {
        const int j = idx - 65536;
        const int op = j >> 8, k = j & 255;
        const int h = op >> 6, dh = op & 63;
        wkp[j] = f2bf(Wk[(dh*4 + h)*256 + k]);
    } else if (idx < 196608) {
        const int j = idx - 131072;
        wv[j] = f2bf(Wv[j]);
    } else if (idx < 327680) {
        const int j = idx - 196608;
        const int o = j >> 8, k = j & 255;
        wcat[o*512 + k] = f2bf(W1[o*512 + k]);
    } else if (idx < 458752) {
        const int j = idx - 327680;
        w2b[j] = f2bf(W2[j]);
    } else if (idx < 459008) {
        const int j = idx - 458752;
        const int h = j >> 6, dh = j & 63;
        bqp[j] = bq[dh*4 + h];
    } else if (idx < 459264) {
        const int j = idx - 459008;
        const int h = j >> 6, dh = j & 63;
        bkp[j] = bk[dh*4 + h];
    } else if (idx < 459776) {
        const int o = idx - 459264;
        float acc = b1[o];
        for (int j = 0; j < 256; ++j) acc += W1[o*512 + 256 + j] * bm[j];
        bfold[o] = acc;
    }
}

// ---------------------------------------------------------------------------
// Weight fold GEMM: wcat[o][256+cp] = sum_j W1[o][256+j] * Wm[j][perm(cp)]
// perm(cp=h*64+dh) -> dh*4+h. 64x64 tiles, K=256. grid (4, 8).
// ---------------------------------------------------------------------------
__global__ __launch_bounds__(256) void fold_w(
    const float* __restrict__ W1, const float* __restrict__ Wm,
    unsigned short* __restrict__ wcat)
{
    __shared__ float As[64][33];
    __shared__ float Bs[32][64];
    const int o0 = blockIdx.y * 64, c0 = blockIdx.x * 64;
    const int tid = threadIdx.x;
    const int tx = tid & 15, ty = tid >> 4;
    float acc[4][4] = {};
    for (int k0 = 0; k0 < 256; k0 += 32) {
        #pragma unroll
        for (int u = 0; u < 8; ++u) {
            const int l = u * 256 + tid;
            As[l >> 5][l & 31] = W1[(o0 + (l >> 5))*512 + 256 + k0 + (l & 31)];
        }
        #pragma unroll
        for (int u = 0; u < 8; ++u) {
            const int l = u * 256 + tid;
            const int cp = c0 + (l & 63), j = k0 + (l >> 6);
            const int h = cp >> 6, dh = cp & 63;
            Bs[l >> 6][l & 63] = Wm[j*256 + dh*4 + h];
        }
        __syncthreads();
        #pragma unroll 8
        for (int kk = 0; kk < 32; ++kk) {
            const float a0 = As[ty*4+0][kk];
            const float a1 = As[ty*4+1][kk];
            const float a2 = As[ty*4+2][kk];
            const float a3 = As[ty*4+3][kk];
            const float4 bv = *(const float4*)&Bs[kk][tx*4];
            acc[0][0]+=a0*bv.x; acc[0][1]+=a0*bv.y; acc[0][2]+=a0*bv.z; acc[0][3]+=a0*bv.w;
            acc[1][0]+=a1*bv.x; acc[1][1]+=a1*bv.y; acc[1][2]+=a1*bv.z; acc[1][3]+=a1*bv.w;
            acc[2][0]+=a2*bv.x; acc[2][1]+=a2*bv.y; acc[2][2]+=a2*bv.z; acc[2][3]+=a2*bv.w;
            acc[3][0]+=a3*bv.x; acc[3][1]+=a3*bv.y; acc[3][2]+=a3*bv.z; acc[3][3]+=a3*bv.w;
        }
        __syncthreads();
    }
    #pragma unroll
    for (int i = 0; i < 4; ++i)
        #pragma unroll
        for (int j = 0; j < 4; ++j)
            wcat[(o0 + ty*4 + i)*512 + 256 + c0 + tx*4 + j] = f2bf(acc[i][j]);
}

// ---------------------------------------------------------------------------
// Transpose-convert x/source: fp32 [b,c,n] -> bf16 [b,n,c].
// ---------------------------------------------------------------------------
__global__ __launch_bounds__(256) void cvt_t(
    const float* __restrict__ x, const float* __restrict__ src,
    unsigned short* __restrict__ xbf, unsigned short* __restrict__ sbf)
{
    __shared__ float T[64][65];
    const int z = blockIdx.z;
    const int b = z & 7;
    const float* in = (z < 8) ? x : src;
    unsigned short* out = (z < 8) ? xbf : sbf;
    const int c0 = blockIdx.y * 64, n0 = blockIdx.x * 64;
    const int tid = threadIdx.x;
    #pragma unroll
    for (int u = 0; u < 16; ++u) {
        const int idx = u * 256 + tid;
        const int nn = idx & 63, cc = idx >> 6;
        T[cc][nn] = in[((size_t)(b*256 + c0 + cc))*2048 + n0 + nn];
    }
    __syncthreads();
    #pragma unroll
    for (int u = 0; u < 16; ++u) {
        const int idx = u * 256 + tid;
        const int c = idx & 63, nn = idx >> 6;
        out[((size_t)(b*2048 + n0 + nn))*256 + c0 + c] = f2bf(T[c][nn]);
    }
}

// ---------------------------------------------------------------------------
// MFMA pointwise-conv body. Tile 128o x 64n, BK=64, 4 waves (2 o x 2 n),
// per-wave 64o x 32n (4x2 frags). Double-buffered LDS (48KB), GLOAD16 staging
// with both-sides XOR swizzle. Virtual channel concat (inA,inB,splitC).
// EPI: 0 = bf16 [b,h,n,64]; 1 = bf16 [b,o,m]; 2 = bf16 [b,n,Cout];
//      4 = fp32 [b,o,n]
// ---------------------------------------------------------------------------
template<int CIN, int EPI>
static __device__ __forceinline__ void conv_body(
    unsigned short* SH,
    const unsigned short* __restrict__ Wb, const float* __restrict__ bias,
    const unsigned short* __restrict__ inA, const unsigned short* __restrict__ inB,
    int splitC, void* __restrict__ outp, int ostride)
{
    const int b  = blockIdx.z & 7;
    const int o0 = blockIdx.y * 128;
    const int n0 = blockIdx.x * 64;
    const int tid = threadIdx.x;
    const int w = tid >> 6, l = tid & 63;
    const int wr = w >> 1, wc = w & 1;
    const int g_ = l >> 4, ln = l & 15;

    f32x4 acc[4][2];
    #pragma unroll
    for (int mi = 0; mi < 4; ++mi)
        #pragma unroll
        for (int nj = 0; nj < 2; ++nj) acc[mi][nj] = (f32x4){0.f, 0.f, 0.f, 0.f};

    auto STAGE = [&](int t, int c) {
        const int k0 = t * 64;
        unsigned short* As = SH + c * 12288;
        unsigned short* Bs = As + 8192;
        #pragma unroll
        for (int u = 0; u < 4; ++u) {
            const int chunk = (w*4 + u)*64 + l;
            const int row = chunk >> 3;
            const int cs = (chunk & 7) ^ (row & 7);
            GLOAD16(Wb + (size_t)(o0 + row)*CIN + k0 + cs*8, As + (w*4 + u)*512);
        }
        const unsigned short* src; int sC, kk;
        if (k0 < splitC) { src = inA; sC = splitC; kk = k0; }
        else             { src = inB; sC = CIN - splitC; kk = k0 - splitC; }
        #pragma unroll
        for (int u = 0; u < 2; ++u) {
            const int chunk = (w*2 + u)*64 + l;
            const int row = chunk >> 3;
            const int cs = (chunk & 7) ^ (row & 7);
            GLOAD16(src + ((size_t)b*N_ + n0 + row)*sC + kk + cs*8, Bs + (w*2 + u)*512);
        }
    };

    auto COMPUTE = [&](int c) {
        const unsigned short* As = SH + c * 12288;
        const unsigned short* Bs = As + 8192;
        #pragma unroll
        for (int ks = 0; ks < 2; ++ks) {
            bf16x8 af[4], bfr[2];
            #pragma unroll
            for (int mi = 0; mi < 4; ++mi) {
                const int row = wr*64 + mi*16 + ln;
                af[mi] = *(const bf16x8*)&As[row*64 + (((ks*4 + g_) ^ (row & 7)) << 3)];
            }
            #pragma unroll
            for (int nj = 0; nj < 2; ++nj) {
                const int row = wc*32 + nj*16 + ln;
                bfr[nj] = *(const bf16x8*)&Bs[row*64 + (((ks*4 + g_) ^ (row & 7)) << 3)];
            }
            #pragma unroll
            for (int mi = 0; mi < 4; ++mi)
                #pragma unroll
                for (int nj = 0; nj < 2; ++nj)
                    acc[mi][nj] = __builtin_amdgcn_mfma_f32_16x16x32_bf16(af[mi], bfr[nj], acc[mi][nj], 0, 0, 0);
        }
    };

    const int nt = CIN / 64;
    STAGE(0, 0);
    __syncthreads();
    int cur = 0;
    for (int t = 0; t < nt; ++t) {
        if (t + 1 < nt) STAGE(t + 1, cur ^ 1);
        COMPUTE(cur);
        __syncthreads();
        cur ^= 1;
    }

    if constexpr (EPI == 0 || EPI == 2) {
        unsigned short* Os = SH;   // [64 n][128 o]
        #pragma unroll
        for (int mi = 0; mi < 4; ++mi) {
            const int ob = wr*64 + mi*16 + g_*4;
            const float4 bv = *(const float4*)&bias[o0 + ob];
            #pragma unroll
            for (int nj = 0; nj < 2; ++nj) {
                const int nl = wc*32 + nj*16 + ln;
                ushort4 us;
                us.x = f2bf(acc[mi][nj][0] + bv.x);
                us.y = f2bf(acc[mi][nj][1] + bv.y);
                us.z = f2bf(acc[mi][nj][2] + bv.z);
                us.w = f2bf(acc[mi][nj][3] + bv.w);
                *(ushort4*)&Os[nl*128 + (((ob >> 3) ^ (nl & 7)) << 3) + (ob & 4)] = us;
            }
        }
        __syncthreads();
        #pragma unroll
        for (int u = 0; u < 4; ++u) {
            const int idx = u*256 + tid;
            const int oc = idx & 15, n = idx >> 4;
            const uint4 v = *(const uint4*)&Os[n*128 + ((oc ^ (n & 7)) << 3)];
            if constexpr (EPI == 0) {
                unsigned short* outT = (unsigned short*)outp;
                const int og = o0 + oc*8;
                *(uint4*)&outT[(((size_t)b*H_ + (og >> 6))*N_ + n0 + n)*64 + (og & 63)] = v;
            } else {
                unsigned short* outS = (unsigned short*)outp;
                *(uint4*)&outS[((size_t)b*N_ + n0 + n)*ostride + o0 + oc*8] = v;
            }
        }
    } else if constexpr (EPI == 1) {
        unsigned short* Os = SH;   // [128 o][72 m]
        #pragma unroll
        for (int mi = 0; mi < 4; ++mi) {
            const int ob = wr*64 + mi*16 + g_*4;
            const float4 bv = *(const float4*)&bias[o0 + ob];
            const float bb[4] = {bv.x, bv.y, bv.z, bv.w};
            #pragma unroll
            for (int nj = 0; nj < 2; ++nj) {
                const int nl = wc*32 + nj*16 + ln;
                #pragma unroll
                for (int r = 0; r < 4; ++r)
                    Os[(ob + r)*72 + nl] = f2bf(acc[mi][nj][r] + bb[r]);
            }
        }
        __syncthreads();
        unsigned short* outV = (unsigned short*)outp;
        #pragma unroll
        for (int u = 0; u < 4; ++u) {
            const int idx = u*256 + tid;
            const int mc = idx & 7, o = idx >> 3;
            const uint4 v = *(const uint4*)&Os[o*72 + mc*8];
            *(uint4*)&outV[((size_t)b*D_ + o0 + o)*(size_t)M_ + n0 + mc*8] = v;
        }
    } else {   // EPI == 4: fp32 [b,o,n]
        float* Of = (float*)SH;   // [128 o][68 n] padded
        #pragma unroll
        for (int mi = 0; mi < 4; ++mi) {
            const int ob = wr*64 + mi*16 + g_*4;
            const float4 bv = *(const float4*)&bias[o0 + ob];
            const float bb[4] = {bv.x, bv.y, bv.z, bv.w};
            #pragma unroll
            for (int nj = 0; nj < 2; ++nj) {
                const int nl = wc*32 + nj*16 + ln;
                #pragma unroll
                for (int r = 0; r < 4; ++r)
                    Of[(ob + r)*68 + nl] = acc[mi][nj][r] + bb[r];
            }
        }
        __syncthreads();
        float* outF = (float*)outp;
        #pragma unroll
        for (int u = 0; u < 8; ++u) {
            const int idx = u*256 + tid;
            const int nc = idx & 15, o = idx >> 4;
            const float4 v = *(const float4*)&Of[o*68 + nc*4];
            *(float4*)&outF[((size_t)b*D_ + o0 + o)*(size_t)N_ + n0 + nc*4] = v;
        }
    }
}

// fused q/k/v conv: grid (32, 2, 24), z: [0,8) q, [8,16) k, [16,24) v
__global__ __launch_bounds__(256, 3) void conv_qkv(
    const unsigned short* __restrict__ wqp, const float* __restrict__ bqp,
    const unsigned short* __restrict__ wkp, const float* __restrict__ bkp,
    const unsigned short* __restrict__ wv,  const float* __restrict__ bv,
    const unsigned short* __restrict__ xbf, const unsigned short* __restrict__ srcbf,
    unsigned short* __restrict__ qt, unsigned short* __restrict__ kt,
    unsigned short* __restrict__ vb)
{
    __shared__ __align__(16) unsigned short SH[24576];
    const int zz = blockIdx.z >> 3;
    if (zz == 0)      conv_body<256, 0>(SH, wqp, bqp, xbf,   xbf,   256, qt, 0);
    else if (zz == 1) conv_body<256, 0>(SH, wkp, bkp, srcbf, srcbf, 256, kt, 0);
    else              conv_body<256, 1>(SH, wv,  bv,  srcbf, srcbf, 256, vb, 0);
}

template<int CIN, int EPI>
__global__ __launch_bounds__(256, 3) void conv_mfma(
    const unsigned short* __restrict__ Wb, const float* __restrict__ bias,
    const unsigned short* __restrict__ inA, const unsigned short* __restrict__ inB,
    int splitC, void* __restrict__ outp)
{
    __shared__ __align__(16) unsigned short SH[24576];
    conv_body<CIN, EPI>(SH, Wb, bias, inA, inB, splitC, outp, gridDim.y * 128);
}

// ---------------------------------------------------------------------------
// Pipelined MFMA flash attention. 1 barrier per m-tile; K/V double-buffered
// via global_load_lds; mask prefetched one tile ahead into registers;
// P LDS round-trip is same-wave (lgkmcnt-only sync); defer-max; setprio.
// ---------------------------------------------------------------------------
__global__ __launch_bounds__(256, 4) void attn_mfma(
    const unsigned short* __restrict__ qt, const unsigned short* __restrict__ kt,
    const unsigned short* __restrict__ vbf, const float* __restrict__ mask,
    unsigned short* __restrict__ ab)
{
    __shared__ __align__(16) unsigned short SH[20480];   // 40 KB
    unsigned short* Kb0 = SH;
    unsigned short* Kb1 = SH + 4096;
    unsigned short* Vb0 = SH + 8192;
    unsigned short* Vb1 = SH + 12288;
    unsigned short* QP  = SH + 16384;   // Q staging, then P

    const int b = blockIdx.z, h = blockIdx.y, n0 = blockIdx.x * 64;
    const int tid = threadIdx.x;
    const int w = tid >> 6, lane = tid & 63;
    const int ln = lane & 15, g = lane >> 4;
    const int rsw = (ln & 7) << 3;

    const unsigned short* qbase = qt + (((size_t)b * H_ + h) * N_ + n0) * 64;
    const unsigned short* kbase = kt + ((size_t)b * H_ + h) * (size_t)M_ * 64;
    const unsigned short* vbase = vbf + (size_t)b * D_ * M_ + (size_t)h * M_;
    const float* mbase = mask + ((size_t)b * N_ + n0 + w*16 + g*4) * (size_t)M_ + ln;

    // prologue: stage Q + K/V tile 0, prefetch mask tile 0
    #pragma unroll
    for (int u = 0; u < 2; ++u) {
        const int chunk = (w*2 + u)*64 + lane;
        const int row = chunk >> 3, cs = (chunk & 7) ^ (row & 7);
        GLOAD16(qbase + row*64 + cs*8, QP + (w*2+u)*512);
        GLOAD16(kbase + row*64 + cs*8, Kb0 + (w*2+u)*512);
        GLOAD16(vbase + (size_t)row*(H_*M_) + cs*8, Vb0 + (w*2+u)*512);
    }
    float mA[16], mB[16];
    #pragma unroll
    for (int r = 0; r < 4; ++r)
        #pragma unroll
        for (int f = 0; f < 4; ++f)
            mA[r*4+f] = mbase[(size_t)r*M_ + f*16];

    f32x4 oacc[4];
    #pragma unroll
    for (int f = 0; f < 4; ++f) oacc[f] = (f32x4){0.f, 0.f, 0.f, 0.f};
    float mrun[4] = {-INFINITY, -INFINITY, -INFINITY, -INFINITY};
    float lrun[4] = {0.f, 0.f, 0.f, 0.f};

    asm volatile("s_waitcnt vmcnt(0)" ::: "memory");
    __builtin_amdgcn_s_barrier();
    __builtin_amdgcn_sched_barrier(0);

    bf16x8 a_q[2];
    #pragma unroll
    for (int ks = 0; ks < 2; ++ks)
        a_q[ks] = *(const bf16x8*)&QP[(w*16 + ln)*64 + ((ks*32 + g*8) ^ rsw)];

    auto ITER = [&](int t, float (&mc)[16], float (&mn)[16]) {
        unsigned short* Kc = (t & 1) ? Kb1 : Kb0;
        unsigned short* Vc = (t & 1) ? Vb1 : Vb0;
        unsigned short* Kn = (t & 1) ? Kb0 : Kb1;
        unsigned short* Vn = (t & 1) ? Vb0 : Vb1;
        if (t + 1 < 32) {
            const int m1 = (t + 1) * 64;
            #pragma unroll
            for (int u = 0; u < 2; ++u) {
                const int chunk = (w*2 + u)*64 + lane;
                const int row = chunk >> 3, cs = (chunk & 7) ^ (row & 7);
                GLOAD16(kbase + (size_t)(m1 + row)*64 + cs*8, Kn + (w*2+u)*512);
                GLOAD16(vbase + (size_t)row*(H_*M_) + m1 + cs*8, Vn + (w*2+u)*512);
            }
            #pragma unroll
            for (int r = 0; r < 4; ++r)
                #pragma unroll
                for (int f = 0; f < 4; ++f)
                    mn[r*4+f] = mbase[(size_t)r*M_ + m1 + f*16];
        }
        // ---- QK^T ----
        f32x4 sacc[4];
        #pragma unroll
        for (int f = 0; f < 4; ++f) sacc[f] = (f32x4){0.f, 0.f, 0.f, 0.f};
        __builtin_amdgcn_s_setprio(1);
        #pragma unroll
        for (int ks = 0; ks < 2; ++ks)
            #pragma unroll
            for (int f = 0; f < 4; ++f) {
                const bf16x8 bk = *(const bf16x8*)&Kc[(f*16 + ln)*64 + ((ks*32 + g*8) ^ rsw)];
                sacc[f] = __builtin_amdgcn_mfma_f32_16x16x32_bf16(a_q[ks], bk, sacc[f], 0, 0, 0);
            }
        __builtin_amdgcn_s_setprio(0);
        // ---- softmax (rows n = w*16 + g*4 + r), defer-max THR=8 ----
        #pragma unroll
        for (int r = 0; r < 4; ++r)
            #pragma unroll
            for (int f = 0; f < 4; ++f)
                sacc[f][r] = sacc[f][r] * 0.125f * mc[r*4+f];
        float tm[4];
        bool need = false;
        #pragma unroll
        for (int r = 0; r < 4; ++r) {
            float t0 = fmaxf(fmaxf(sacc[0][r], sacc[1][r]), fmaxf(sacc[2][r], sacc[3][r]));
            t0 = fmaxf(t0, __shfl_xor(t0, 1, 16));
            t0 = fmaxf(t0, __shfl_xor(t0, 2, 16));
            t0 = fmaxf(t0, __shfl_xor(t0, 4, 16));
            t0 = fmaxf(t0, __shfl_xor(t0, 8, 16));
            tm[r] = t0;
            need |= (t0 > mrun[r] + 8.f);
        }
        if (__any(need)) {
            #pragma unroll
            for (int r = 0; r < 4; ++r) {
                const float nm = fmaxf(mrun[r], tm[r]);
                const float corr = __expf(mrun[r] - nm);
                mrun[r] = nm;
                lrun[r] *= corr;
                #pragma unroll
                for (int f = 0; f < 4; ++f) oacc[f][r] *= corr;
            }
        }
        #pragma unroll
        for (int r = 0; r < 4; ++r) {
            const int row = w*16 + g*4 + r;
            const int rs2 = (row & 7) << 3;
            float ps = 0.f;
            #pragma unroll
            for (int f = 0; f < 4; ++f) {
                const float p = __expf(sacc[f][r] - mrun[r]);
                ps += p;
                QP[row*64 + ((f*16 + ln) ^ rs2)] = f2bf(p);
            }
            ps += __shfl_xor(ps, 1, 16);
            ps += __shfl_xor(ps, 2, 16);
            ps += __shfl_xor(ps, 4, 16);
            ps += __shfl_xor(ps, 8, 16);
            lrun[r] += ps;
        }
        asm volatile("s_waitcnt lgkmcnt(0)" ::: "memory");
        __builtin_amdgcn_sched_barrier(0);
        // ---- PV ----
        __builtin_amdgcn_s_setprio(1);
        #pragma unroll
        for (int ks = 0; ks < 2; ++ks) {
            const bf16x8 ap = *(const bf16x8*)&QP[(w*16 + ln)*64 + ((ks*32 + g*8) ^ rsw)];
            #pragma unroll
            for (int fd = 0; fd < 4; ++fd) {
                const bf16x8 bv = *(const bf16x8*)&Vc[(fd*16 + ln)*64 + ((ks*32 + g*8) ^ rsw)];
                oacc[fd] = __builtin_amdgcn_mfma_f32_16x16x32_bf16(ap, bv, oacc[fd], 0, 0, 0);
            }
        }
        __builtin_amdgcn_s_setprio(0);
        asm volatile("s_waitcnt vmcnt(0)" ::: "memory");
        __builtin_amdgcn_s_barrier();
        __builtin_amdgcn_sched_barrier(0);
    };

    #pragma unroll 1
    for (int tt = 0; tt < 32; tt += 2) {
        ITER(tt,     mA, mB);
        ITER(tt + 1, mB, mA);
    }

    // epilogue: O -> bf16 ab[b, n, h*64+dh] via swizzled LDS bounce
    unsigned short* Os = SH;
    float inv[4];
    #pragma unroll
    for (int r = 0; r < 4; ++r) inv[r] = 1.f / lrun[r];
    #pragma unroll
    for (int fd = 0; fd < 4; ++fd) {
        const int dh = fd*16 + ln;
        const int cd = dh >> 3;
        #pragma unroll
        for (int r = 0; r < 4; ++r) {
            const int n = w*16 + g*4 + r;
            Os[n*64 + ((cd ^ (n & 7)) << 3) + (dh & 7)] = f2bf(oacc[fd][r] * inv[r]);
        }
    }
    asm volatile("s_waitcnt lgkmcnt(0)" ::: "memory");
    __builtin_amdgcn_s_barrier();
    __builtin_amdgcn_sched_barrier(0);
    #pragma unroll
    for (int u = 0; u < 2; ++u) {
        const int idx = u*256 + tid;
        const int ch = idx & 7, n = idx >> 3;
        const uint4 v = *(const uint4*)&Os[n*64 + ((ch ^ (n & 7)) << 3)];
        *(uint4*)&ab[((size_t)b*N_ + n0 + n)*256 + h*64 + ch*8] = v;
    }
}

// ---------------------------------------------------------------------------
// InstanceNorm stats/apply. y1: bf16 [b,n,512]; stats fp32 [b][512][2].
// ---------------------------------------------------------------------------
__global__ __launch_bounds__(256) void in_stats(
    const unsigned short* __restrict__ y1, float* __restrict__ st)
{
    const int b = blockIdx.y, nch = blockIdx.x, tid = threadIdx.x;
    const int c = tid * 2;
    float sa = 0.f, sa2 = 0.f, sb = 0.f, sb2 = 0.f;
    #pragma unroll 4
    for (int r = 0; r < 32; ++r) {
        const int n = nch*32 + r;
        const unsigned int u = *(const unsigned int*)&y1[((size_t)b*N_ + n)*512 + c];
        const float a = bf2f_lo(u), bb = bf2f_hi(u);
        sa += a; sa2 += a*a; sb += bb; sb2 += bb*bb;
    }
    atomicAdd(&st[(b*512 + c)*2 + 0], sa);
    atomicAdd(&st[(b*512 + c)*2 + 1], sa2);
    atomicAdd(&st[(b*512 + c + 1)*2 + 0], sb);
    atomicAdd(&st[(b*512 + c + 1)*2 + 1], sb2);
}

__global__ __launch_bounds__(256) void in_apply(
    const unsigned short* __restrict__ y1, const float* __restrict__ st,
    unsigned short* __restrict__ yo)
{
    const int b = blockIdx.y, nch = blockIdx.x, tid = threadIdx.x;
    const int c = tid * 2;
    const float mua = st[(b*512 + c)*2 + 0] * (1.f/2048.f);
    const float vara = st[(b*512 + c)*2 + 1] * (1.f/2048.f) - mua*mua;
    const float inva = rsqrtf(vara + 1e-5f);
    const float mub = st[(b*512 + c + 1)*2 + 0] * (1.f/2048.f);
    const float varb = st[(b*512 + c + 1)*2 + 1] * (1.f/2048.f) - mub*mub;
    const float invb = rsqrtf(varb + 1e-5f);
    #pragma unroll 4
    for (int r = 0; r < 32; ++r) {
        const int n = nch*32 + r;
        const size_t off = ((size_t)b*N_ + n)*512 + c;
        const unsigned int u = *(const unsigned int*)&y1[off];
        const float na = fmaxf((bf2f_lo(u) - mua) * inva, 0.f);
        const float nb = fmaxf((bf2f_hi(u) - mub) * invb, 0.f);
        *(unsigned int*)&yo[off] = (unsigned int)f2bf(na) | ((unsigned int)f2bf(nb) << 16);
    }
}

// ---------------------------------------------------------------------------
extern "C" void kernel_launch(void* const* d_in, const int* in_sizes, int n_in,
                              void* d_out, int out_size, void* d_ws, size_t ws_size,
                              hipStream_t stream)
{
    const float* x    = (const float*)d_in[0];
    const float* srcp = (const float*)d_in[1];
    const float* mask = (const float*)d_in[2];
    const float* Wq = (const float*)d_in[3];
    const float* bq = (const float*)d_in[4];
    const float* Wk = (const float*)d_in[5];
    const float* bk = (const float*)d_in[6];
    const float* Wv = (const float*)d_in[7];
    const float* bv = (const float*)d_in[8];
    const float* Wm = (const float*)d_in[9];
    const float* bm = (const float*)d_in[10];
    const float* W1 = (const float*)d_in[11];
    const float* b1 = (const float*)d_in[12];
    const float* W2 = (const float*)d_in[13];
    const float* b2 = (const float*)d_in[14];
    float* out = (float*)d_out;

    char* wsb = (char*)d_ws;
    const size_t MB = 1 << 20;
    unsigned short* xbf   = (unsigned short*)(wsb + 0*MB);    // [b,n,256]
    unsigned short* srcbf = (unsigned short*)(wsb + 8*MB);    // [b,m,256]
    unsigned short* ab    = (unsigned short*)(wsb + 8*MB);    // over srcbf (dead post-qkv)
    unsigned short* qt_   = (unsigned short*)(wsb + 16*MB);   // [b,h,n,64]
    unsigned short* kt_   = (unsigned short*)(wsb + 24*MB);   // [b,h,m,64]
    unsigned short* y1    = (unsigned short*)(wsb + 16*MB);   // [b,n,512] over qt/kt (dead post-attn)
    unsigned short* vb_   = (unsigned short*)(wsb + 32*MB);   // [b,d,m]
    unsigned short* ybf   = (unsigned short*)(wsb + 32*MB);   // [b,n,512] over vb (dead post-attn)
    char* wbase = wsb + 48*MB;
    unsigned short* wqp  = (unsigned short*)(wbase + 0);
    unsigned short* wkp  = (unsigned short*)(wbase + 131072);
    unsigned short* wv   = (unsigned short*)(wbase + 262144);
    unsigned short* wcat = (unsigned short*)(wbase + 393216);   // [512][512]
    unsigned short* w2b  = (unsigned short*)(wbase + 917504);   // [256][512]
    float* bqp   = (float*)(wbase + 1179648);
    float* bkp   = (float*)(wbase + 1180672);
    float* bfold = (float*)(wbase + 1181696);
    float* stats = (float*)(wbase + 1183744);                   // [8][512][2]

    const dim3 blk(256);

    cvt_w<<<dim3(1796), blk, 0, stream>>>(Wq, Wk, Wv, W1, W2, bq, bk, b1, bm,
                                          wqp, wkp, wv, wcat, w2b, bqp, bkp, bfold);
    fold_w<<<dim3(4, 8), blk, 0, stream>>>(W1, Wm, wcat);
    cvt_t<<<dim3(32, 4, 16), blk, 0, stream>>>(x, srcp, xbf, srcbf);
    hipMemsetAsync(stats, 0, 8*512*2*sizeof(float), stream);

    conv_qkv<<<dim3(32, 2, 24), blk, 0, stream>>>(wqp, bqp, wkp, bkp, wv, bv,
                                                  xbf, srcbf, qt_, kt_, vb_);

    attn_mfma<<<dim3(32, 4, 8), blk, 0, stream>>>(qt_, kt_, vb_, mask, ab);

    // y1 = Wcat . [x ; attn] + bfold  (merge conv folded into W1)
    conv_mfma<512, 2><<<dim3(32, 4, 8), blk, 0, stream>>>(wcat, bfold, xbf, ab, 256, y1);

    in_stats<<<dim3(64, 8), blk, 0, stream>>>(y1, stats);
    in_apply<<<dim3(64, 8), blk, 0, stream>>>(y1, stats, ybf);

    conv_mfma<512, 4><<<dim3(32, 2, 8), blk, 0, stream>>>(w2b, b2, ybf, ybf, 512, out);
}